// Round 3
// baseline (202.860 us; speedup 1.0000x reference)
//
#include <hip/hip_runtime.h>
#include <stdint.h>

#define BSz 4096   // B*S tokens
#define Ddim 1024
#define Fdim 4096
#define Edim 4
#define Rdim 4

typedef __attribute__((ext_vector_type(8))) short bf16x8;
typedef __attribute__((ext_vector_type(4))) float f32x4;

__device__ __forceinline__ unsigned short f2bf(float f) {
  union { float f; uint32_t u; } c; c.f = f;
  return (unsigned short)((c.u + 0x7fffu + ((c.u >> 16) & 1u)) >> 16);
}

// ---------------- fp32 -> bf16 conversion (vectorized) ----------------
__global__ __launch_bounds__(256) void cvt_kernel(const float* __restrict__ in,
                                                  unsigned short* __restrict__ out,
                                                  int n4) {
  int i = blockIdx.x * 256 + threadIdx.x;
  if (i < n4) {
    float4 v = ((const float4*)in)[i];
    ushort4 o;
    o.x = f2bf(v.x); o.y = f2bf(v.y); o.z = f2bf(v.z); o.w = f2bf(v.w);
    ((ushort4*)out)[i] = o;
  }
}

// ---------------- router: logits -> softmax -> top2 + lora_low ----------------
// meta[t][0..15]: e0, e1, w0, w1, ll0[0..3], ll1[0..3], pad
__global__ __launch_bounds__(256) void router_kernel(const float* __restrict__ x,
                                                     const float* __restrict__ Wg,
                                                     const float* __restrict__ bg,
                                                     const float* __restrict__ Aw,
                                                     float* __restrict__ meta) {
  __shared__ float xs[Ddim];
  __shared__ float dots[Edim + Edim * Rdim];
  const int t = blockIdx.x;
  const float4* xt = (const float4*)(x + (size_t)t * Ddim);
  for (int i = threadIdx.x; i < Ddim / 4; i += 256) ((float4*)xs)[i] = xt[i];
  __syncthreads();
  const int wave = threadIdx.x >> 6, lane = threadIdx.x & 63;
  for (int d = wave * 5; d < wave * 5 + 5; ++d) {
    const float* wrow = (d < Edim) ? (Wg + (size_t)d * Ddim)
                                   : (Aw + (size_t)(d - Edim) * Ddim);
    float s = 0.f;
    for (int i = lane; i < Ddim; i += 64) s += xs[i] * wrow[i];
    for (int off = 32; off; off >>= 1) s += __shfl_down(s, off);
    if (lane == 0) dots[d] = s;
  }
  __syncthreads();
  if (threadIdx.x == 0) {
    float p[Edim];
    float m = -1e30f;
    for (int e = 0; e < Edim; ++e) { p[e] = dots[e] + bg[e]; m = fmaxf(m, p[e]); }
    float sum = 0.f;
    for (int e = 0; e < Edim; ++e) { p[e] = expf(p[e] - m); sum += p[e]; }
    const float inv = 1.f / sum;
    for (int e = 0; e < Edim; ++e) p[e] *= inv;
    int e0 = 0;
    for (int e = 1; e < Edim; ++e) if (p[e] > p[e0]) e0 = e;
    int e1 = (e0 == 0) ? 1 : 0;
    for (int e = 0; e < Edim; ++e) if (e != e0 && p[e] > p[e1]) e1 = e;
    float* mt = meta + (size_t)t * 16;
    mt[0] = (float)e0; mt[1] = (float)e1; mt[2] = p[e0]; mt[3] = p[e1];
    for (int r = 0; r < Rdim; ++r) {
      mt[4 + r] = dots[Edim + e0 * Rdim + r];
      mt[8 + r] = dots[Edim + e1 * Rdim + r];
    }
    mt[12] = 0.f; mt[13] = 0.f; mt[14] = 0.f; mt[15] = 0.f;
  }
}

// ---------------- ring-4 deep-pipelined NT bf16 GEMM ----------------
// C[M,N] = A[M,K] * B[N,K]^T.  BK=32, 4-slot LDS ring, counted vmcnt(8),
// XOR-swizzled LDS (pre-swizzled global source, linear gload_lds dest).
// EPI==0: fused MoE epilogue -> g[t,f] (bf16).  EPI==1: plain fp32 store.
template <int BM, int BN, int WMv, int WNv, int EPI>
__global__ __launch_bounds__(WMv * WNv * 64, 2)
void gemm_ring(const unsigned short* __restrict__ Ag,
               const unsigned short* __restrict__ Bg,
               int M, int N, int K,
               const float* __restrict__ meta,
               const float* __restrict__ B2,
               unsigned short* __restrict__ outg,
               float* __restrict__ outf) {
  constexpr int BK = 32;
  constexpr int NTH = WMv * WNv * 64;
  constexpr int WROWS = BM / WMv;
  constexpr int WCOLS = BN / WNv;
  constexpr int MR = WROWS / 16;
  constexpr int NR = WCOLS / 16;
  constexpr int RPR = NTH / 4;          // rows staged per round (4 thr/row @ BK=32)
  constexpr int NRA = BM / RPR;
  constexpr int NRB = BN / RPR;

  __shared__ __align__(16) unsigned short sA[4][BM * BK];
  __shared__ __align__(16) unsigned short sB[4][BN * BK];

  const int tid = threadIdx.x;
  const int lane = tid & 63;
  const int wave = tid >> 6;
  const int wr = wave / WNv, wc = wave % WNv;
  const int l16 = lane & 15, lhi = lane >> 4;

  // ---- XCD-aware bijective block swizzle (nwg % 8 == 0 for both grids) ----
  const int nwg = gridDim.x * gridDim.y;
  const int lin = blockIdx.y * gridDim.x + blockIdx.x;
  const int cpx = nwg >> 3;
  const int swz = (lin & 7) * cpx + (lin >> 3);
  const int bx = swz % gridDim.x;
  const int by = swz / gridDim.x;
  const int bm = by * BM, bn = bx * BN;

  f32x4 acc[MR][NR] = {};

  // ---- staging geometry: thread covers 16B; source column pre-swizzled ----
  const int srow = tid >> 2;                                   // row within round
  const int swc = ((tid & 3) ^ ((tid >> 3) & 3)) * 8;          // swizzled src col (elems)
  const int ldsoff = tid * 8;                                  // linear LDS dest (elems)

  auto stage = [&](int slot, int kt) {
#pragma unroll
    for (int rr = 0; rr < NRA; ++rr)
      __builtin_amdgcn_global_load_lds(
          (const __attribute__((address_space(1))) void*)(Ag + (size_t)(bm + srow + rr * RPR) * K + kt + swc),
          (__attribute__((address_space(3))) void*)(&sA[slot][ldsoff + rr * RPR * BK]), 16, 0, 0);
#pragma unroll
    for (int rr = 0; rr < NRB; ++rr)
      __builtin_amdgcn_global_load_lds(
          (const __attribute__((address_space(1))) void*)(Bg + (size_t)(bn + srow + rr * RPR) * K + kt + swc),
          (__attribute__((address_space(3))) void*)(&sB[slot][ldsoff + rr * RPR * BK]), 16, 0, 0);
  };

  // read-side swizzle: slot' = lhi ^ ((row>>1)&3); row = base + l16 with base%16==0
  const int sl8 = (lhi ^ ((l16 >> 1) & 3)) * 8;

  auto compute = [&](int slot) {
    bf16x8 af[MR], bfv[NR];
#pragma unroll
    for (int i = 0; i < MR; ++i)
      af[i] = *(const bf16x8*)(&sA[slot][(wr * WROWS + i * 16 + l16) * BK + sl8]);
#pragma unroll
    for (int j = 0; j < NR; ++j)
      bfv[j] = *(const bf16x8*)(&sB[slot][(wc * WCOLS + j * 16 + l16) * BK + sl8]);
    __builtin_amdgcn_s_setprio(1);
#pragma unroll
    for (int i = 0; i < MR; ++i)
#pragma unroll
      for (int j = 0; j < NR; ++j)
        acc[i][j] = __builtin_amdgcn_mfma_f32_16x16x32_bf16(af[i], bfv[j], acc[i][j], 0, 0, 0);
    __builtin_amdgcn_s_setprio(0);
  };

  const int NT = K / BK;
  // prologue: 3 tiles in flight
  stage(0, 0);
  stage(1, BK);
  stage(2, 2 * BK);

  for (int t = 0; t < NT; ++t) {
    if (t < NT - 2)       asm volatile("s_waitcnt vmcnt(8)" ::: "memory");
    else if (t == NT - 2) asm volatile("s_waitcnt vmcnt(4)" ::: "memory");
    else                  asm volatile("s_waitcnt vmcnt(0)" ::: "memory");
    __builtin_amdgcn_s_barrier();
    asm volatile("" ::: "memory");
    if (t + 3 < NT) stage((t + 3) & 3, (t + 3) * BK);   // issue-early, lands later
    compute(t & 3);
    asm volatile("" ::: "memory");
    __builtin_amdgcn_s_barrier();
  }

  if (EPI == 0) {
    // g[t,f] = sum_{e in top2} w_e * relu(base + <ll_e, B2[e,f,:]>)
#pragma unroll
    for (int mi = 0; mi < MR; ++mi) {
#pragma unroll
      for (int r = 0; r < 4; ++r) {
        const int t = bm + wr * WROWS + mi * 16 + lhi * 4 + r;
        const float* mt = meta + (size_t)t * 16;
        const int e0 = (int)mt[0], e1 = (int)mt[1];
        const float w0 = mt[2], w1 = mt[3];
        const float4 l0 = *(const float4*)(mt + 4);
        const float4 l1 = *(const float4*)(mt + 8);
#pragma unroll
        for (int ni = 0; ni < NR; ++ni) {
          const int f = bn + wc * WCOLS + ni * 16 + l16;
          const float4 b0 = *(const float4*)(B2 + ((size_t)e0 * Fdim + f) * Rdim);
          const float4 b1 = *(const float4*)(B2 + ((size_t)e1 * Fdim + f) * Rdim);
          const float a = acc[mi][ni][r];
          const float lora0 = l0.x * b0.x + l0.y * b0.y + l0.z * b0.z + l0.w * b0.w;
          const float lora1 = l1.x * b1.x + l1.y * b1.y + l1.z * b1.z + l1.w * b1.w;
          const float gv = w0 * fmaxf(a + lora0, 0.f) + w1 * fmaxf(a + lora1, 0.f);
          outg[(size_t)t * Fdim + f] = f2bf(gv);
        }
      }
    }
  } else {
#pragma unroll
    for (int mi = 0; mi < MR; ++mi)
#pragma unroll
      for (int ni = 0; ni < NR; ++ni)
#pragma unroll
        for (int r = 0; r < 4; ++r) {
          const int t = bm + wr * WROWS + mi * 16 + lhi * 4 + r;
          const int dcol = bn + wc * WCOLS + ni * 16 + l16;
          outf[(size_t)t * N + dcol] = acc[mi][ni][r];
        }
  }
}

extern "C" void kernel_launch(void* const* d_in, const int* in_sizes, int n_in,
                              void* d_out, int out_size, void* d_ws, size_t ws_size,
                              hipStream_t stream) {
  const float* x  = (const float*)d_in[0];
  const float* Wg = (const float*)d_in[1];
  const float* bg = (const float*)d_in[2];
  const float* Wi = (const float*)d_in[3];
  const float* Wo = (const float*)d_in[4];
  const float* Aw = (const float*)d_in[5];
  const float* B2 = (const float*)d_in[6];
  float* out = (float*)d_out;

  // workspace layout (bf16 as ushort)
  unsigned short* xb  = (unsigned short*)d_ws;                 // [BSz][Ddim]   8 MB
  unsigned short* wib = xb  + (size_t)BSz  * Ddim;             // [Fdim][Ddim]  8 MB
  unsigned short* wob = wib + (size_t)Fdim * Ddim;             // [Ddim][Fdim]  8 MB
  unsigned short* g   = wob + (size_t)Ddim * Fdim;             // [BSz][Fdim]  32 MB
  float* meta = (float*)(g + (size_t)BSz * Fdim);              // [BSz][16]   256 KB

  const int n4x = BSz * Ddim / 4;   // == Fdim*Ddim/4 == Ddim*Fdim/4
  cvt_kernel<<<(n4x + 255) / 256, 256, 0, stream>>>(x,  xb,  n4x);
  cvt_kernel<<<(n4x + 255) / 256, 256, 0, stream>>>(Wi, wib, n4x);
  cvt_kernel<<<(n4x + 255) / 256, 256, 0, stream>>>(Wo, wob, n4x);

  router_kernel<<<BSz, 256, 0, stream>>>(x, Wg, bg, Aw, meta);

  // GEMM1: base = x * Wi^T, fused lora+relu+combine epilogue -> g (bf16)
  // 128x128 tile, grid 32x32 = 1024 blocks
  gemm_ring<128, 128, 2, 2, 0><<<dim3(Fdim / 128, BSz / 128), 256, 0, stream>>>(
      xb, wib, BSz, Fdim, Ddim, meta, B2, g, nullptr);

  // GEMM2: out = g * Wo^T (fp32 store), grid 8x32 = 256 blocks, K=4096
  gemm_ring<128, 128, 2, 2, 1><<<dim3(Ddim / 128, BSz / 128), 256, 0, stream>>>(
      g, wob, BSz, Ddim, Fdim, nullptr, nullptr, nullptr, out);
}

// Round 4
// 194.203 us; speedup vs baseline: 1.0446x; 1.0446x over previous
//
#include <hip/hip_runtime.h>
#include <stdint.h>

#define BSz 4096   // B*S tokens
#define Ddim 1024
#define Fdim 4096
#define Edim 4
#define Rdim 4

typedef __attribute__((ext_vector_type(8))) short bf16x8;
typedef __attribute__((ext_vector_type(4))) float f32x4;

__device__ __forceinline__ unsigned short f2bf(float f) {
  union { float f; uint32_t u; } c; c.f = f;
  return (unsigned short)((c.u + 0x7fffu + ((c.u >> 16) & 1u)) >> 16);
}

#define BARX() do { asm volatile("" ::: "memory"); __builtin_amdgcn_s_barrier(); asm volatile("" ::: "memory"); } while (0)

// ---------------- zero d_out (graph-safe, deterministic base for atomics) ----
__global__ __launch_bounds__(256) void zero_f32(float* __restrict__ p, int n4) {
  int i = blockIdx.x * 256 + threadIdx.x;
  if (i < n4) ((float4*)p)[i] = make_float4(0.f, 0.f, 0.f, 0.f);
}

// ---------------- fp32 -> bf16 conversion (vectorized) ----------------
__global__ __launch_bounds__(256) void cvt_kernel(const float* __restrict__ in,
                                                  unsigned short* __restrict__ out,
                                                  int n4) {
  int i = blockIdx.x * 256 + threadIdx.x;
  if (i < n4) {
    float4 v = ((const float4*)in)[i];
    ushort4 o;
    o.x = f2bf(v.x); o.y = f2bf(v.y); o.z = f2bf(v.z); o.w = f2bf(v.w);
    ((ushort4*)out)[i] = o;
  }
}

// ---------------- router: logits -> softmax -> top2 + lora_low ----------------
__global__ __launch_bounds__(256) void router_kernel(const float* __restrict__ x,
                                                     const float* __restrict__ Wg,
                                                     const float* __restrict__ bg,
                                                     const float* __restrict__ Aw,
                                                     float* __restrict__ meta) {
  __shared__ float xs[Ddim];
  __shared__ float dots[Edim + Edim * Rdim];
  const int t = blockIdx.x;
  const float4* xt = (const float4*)(x + (size_t)t * Ddim);
  for (int i = threadIdx.x; i < Ddim / 4; i += 256) ((float4*)xs)[i] = xt[i];
  __syncthreads();
  const int wave = threadIdx.x >> 6, lane = threadIdx.x & 63;
  for (int d = wave * 5; d < wave * 5 + 5; ++d) {
    const float* wrow = (d < Edim) ? (Wg + (size_t)d * Ddim)
                                   : (Aw + (size_t)(d - Edim) * Ddim);
    float s = 0.f;
    for (int i = lane; i < Ddim; i += 64) s += xs[i] * wrow[i];
    for (int off = 32; off; off >>= 1) s += __shfl_down(s, off);
    if (lane == 0) dots[d] = s;
  }
  __syncthreads();
  if (threadIdx.x == 0) {
    float p[Edim];
    float m = -1e30f;
    for (int e = 0; e < Edim; ++e) { p[e] = dots[e] + bg[e]; m = fmaxf(m, p[e]); }
    float sum = 0.f;
    for (int e = 0; e < Edim; ++e) { p[e] = expf(p[e] - m); sum += p[e]; }
    const float inv = 1.f / sum;
    for (int e = 0; e < Edim; ++e) p[e] *= inv;
    int e0 = 0;
    for (int e = 1; e < Edim; ++e) if (p[e] > p[e0]) e0 = e;
    int e1 = (e0 == 0) ? 1 : 0;
    for (int e = 0; e < Edim; ++e) if (e != e0 && p[e] > p[e1]) e1 = e;
    float* mt = meta + (size_t)t * 16;
    mt[0] = (float)e0; mt[1] = (float)e1; mt[2] = p[e0]; mt[3] = p[e1];
    for (int r = 0; r < Rdim; ++r) {
      mt[4 + r] = dots[Edim + e0 * Rdim + r];
      mt[8 + r] = dots[Edim + e1 * Rdim + r];
    }
    mt[12] = 0.f; mt[13] = 0.f; mt[14] = 0.f; mt[15] = 0.f;
  }
}

// ---------------- 8-phase 256x256 NT bf16 GEMM (m201-style template) --------
// C[M,N] = A[M,K_rowstride] (rows bm..bm+255) * B[N rows, same K]^T over a
// K-slice [kbase, kbase+kslice). 8 waves (2M x 4N), BK=64 split in 2 k-halves,
// LDS = 2 dbuf x 2 khalf x 256 x 32 per matrix = 128 KB total.
// Per phase: ds_read frags || stage 1 half (2 gload_lds) -> 16 MFMA -> barrier.
// vmcnt(4) twice per K-tile (never 0 except last tile).
// EPI==0: fused MoE epilogue -> outg bf16.  EPI==1: f32 atomicAdd into outf.
template <int EPI>
__global__ __launch_bounds__(512, 2)
void gemm8p(const unsigned short* __restrict__ Ag,
            const unsigned short* __restrict__ Bg,
            int K, int kslice, int Ncols,
            const float* __restrict__ meta,
            const float* __restrict__ B2,
            unsigned short* __restrict__ outg,
            float* __restrict__ outf) {
  __shared__ __align__(16) unsigned short sA[2 * 2 * 256 * 32];  // 64 KB
  __shared__ __align__(16) unsigned short sB[2 * 2 * 256 * 32];  // 64 KB

  const int tid = threadIdx.x;
  const int lane = tid & 63;
  const int wave = tid >> 6;            // 0..7
  const int wm = wave >> 2, wn = wave & 3;
  const int l16 = lane & 15, lhi = lane >> 4;

  // XCD-aware bijective swizzle on the xy grid (per z-slice)
  const int nwg = gridDim.x * gridDim.y;
  const int lin = blockIdx.y * gridDim.x + blockIdx.x;
  const int cpx = nwg >> 3;
  const int swz = (lin & 7) * cpx + (lin >> 3);
  const int bx = swz % gridDim.x, by = swz / gridDim.x;
  const int bm = by * 256, bn = bx * 256;
  const int kbase = blockIdx.z * kslice;
  const int NT = kslice / 64;

  f32x4 acc[8][4] = {};

  // staging geometry: thread covers 16B; idx16 = rr*512+tid; row=idx16>>2, c=idx16&3
  const int srow = tid >> 2;                         // 0..127 (round 0)
  const int skoff = ((tid & 3) ^ ((srow >> 1) & 3)) * 8;   // inverse-swizzled src col
  // read-side swizzle (lane-constant): chunk = lhi ^ ((row>>1)&3), row%32 gives (l16>>1)&3
  const int rc8 = (lhi ^ ((l16 >> 1) & 3)) * 8;

  auto stageA = [&](int slot, int kh, int kt2) {
    unsigned short* reg = sA + ((slot * 2 + kh) << 13);
    const size_t g0 = (size_t)(bm + srow) * K + kbase + kt2 + kh * 32 + skoff;
    __builtin_amdgcn_global_load_lds(
        (const __attribute__((address_space(1))) void*)(Ag + g0),
        (__attribute__((address_space(3))) void*)(reg + tid * 8), 16, 0, 0);
    __builtin_amdgcn_global_load_lds(
        (const __attribute__((address_space(1))) void*)(Ag + g0 + (size_t)128 * K),
        (__attribute__((address_space(3))) void*)(reg + 4096 + tid * 8), 16, 0, 0);
  };
  auto stageB = [&](int slot, int kh, int kt2) {
    unsigned short* reg = sB + ((slot * 2 + kh) << 13);
    const size_t g0 = (size_t)(bn + srow) * K + kbase + kt2 + kh * 32 + skoff;
    __builtin_amdgcn_global_load_lds(
        (const __attribute__((address_space(1))) void*)(Bg + g0),
        (__attribute__((address_space(3))) void*)(reg + tid * 8), 16, 0, 0);
    __builtin_amdgcn_global_load_lds(
        (const __attribute__((address_space(1))) void*)(Bg + g0 + (size_t)128 * K),
        (__attribute__((address_space(3))) void*)(reg + 4096 + tid * 8), 16, 0, 0);
  };

  // prologue: stage tile 0 fully (order Ak0,Bk0,Ak1,Bk1) -> 8 loads/thread
  stageA(0, 0, 0); stageB(0, 0, 0); stageA(0, 1, 0); stageB(0, 1, 0);

  for (int t = 0; t < NT; ++t) {
    const int slot = t & 1, nslot = slot ^ 1;
    const int kt2n = (t + 1) * 64;
    const bool pf = (t + 1 < NT);

#pragma unroll
    for (int kh = 0; kh < 2; ++kh) {
      if (kh == 0) {
        asm volatile("s_waitcnt vmcnt(4)" ::: "memory");   // tile t k-half0 landed
      } else {
        if (pf) asm volatile("s_waitcnt vmcnt(4)" ::: "memory");  // k-half1 landed
        else    asm volatile("s_waitcnt vmcnt(0)" ::: "memory");
      }
      BARX();                                              // all waves' shares landed
      const unsigned short* As = sA + ((slot * 2 + kh) << 13);
      const unsigned short* Bs = sB + ((slot * 2 + kh) << 13);
      bf16x8 bfr[4], afr[4];

      // ---- phase mh=0: load B+A frags, stage A-half of t+1, 16 MFMA ----
#pragma unroll
      for (int ni = 0; ni < 4; ++ni)
        bfr[ni] = *(const bf16x8*)(Bs + (wn * 64 + ni * 16 + l16) * 32 + rc8);
#pragma unroll
      for (int mi = 0; mi < 4; ++mi)
        afr[mi] = *(const bf16x8*)(As + (wm * 128 + mi * 16 + l16) * 32 + rc8);
      if (pf) stageA(nslot, kh, kt2n);
      __builtin_amdgcn_s_setprio(1);
#pragma unroll
      for (int mi = 0; mi < 4; ++mi)
#pragma unroll
        for (int ni = 0; ni < 4; ++ni)
          acc[mi][ni] = __builtin_amdgcn_mfma_f32_16x16x32_bf16(afr[mi], bfr[ni], acc[mi][ni], 0, 0, 0);
      __builtin_amdgcn_s_setprio(0);
      BARX();

      // ---- phase mh=1: load A frags (rows +64), stage B-half of t+1, 16 MFMA ----
#pragma unroll
      for (int mi = 0; mi < 4; ++mi)
        afr[mi] = *(const bf16x8*)(As + (wm * 128 + 64 + mi * 16 + l16) * 32 + rc8);
      if (pf) stageB(nslot, kh, kt2n);
      __builtin_amdgcn_s_setprio(1);
#pragma unroll
      for (int mi = 0; mi < 4; ++mi)
#pragma unroll
        for (int ni = 0; ni < 4; ++ni)
          acc[4 + mi][ni] = __builtin_amdgcn_mfma_f32_16x16x32_bf16(afr[mi], bfr[ni], acc[4 + mi][ni], 0, 0, 0);
      __builtin_amdgcn_s_setprio(0);
      BARX();
    }
  }

  if (EPI == 0) {
    // g[t,f] = sum_{e in top2} w_e * relu(base + <ll_e, B2[e,f,:]>)
#pragma unroll
    for (int mh = 0; mh < 2; ++mh)
#pragma unroll
      for (int mi = 0; mi < 4; ++mi) {
#pragma unroll
        for (int r = 0; r < 4; ++r) {
          const int row = bm + wm * 128 + mh * 64 + mi * 16 + lhi * 4 + r;
          const float* mt = meta + (size_t)row * 16;
          const int e0 = (int)mt[0], e1 = (int)mt[1];
          const float w0 = mt[2], w1 = mt[3];
          const float4 l0 = *(const float4*)(mt + 4);
          const float4 l1 = *(const float4*)(mt + 8);
#pragma unroll
          for (int ni = 0; ni < 4; ++ni) {
            const int f = bn + wn * 64 + ni * 16 + l16;
            const float4 b0 = *(const float4*)(B2 + ((size_t)e0 * Fdim + f) * Rdim);
            const float4 b1 = *(const float4*)(B2 + ((size_t)e1 * Fdim + f) * Rdim);
            const float a = acc[mh * 4 + mi][ni][r];
            const float lora0 = l0.x * b0.x + l0.y * b0.y + l0.z * b0.z + l0.w * b0.w;
            const float lora1 = l1.x * b1.x + l1.y * b1.y + l1.z * b1.z + l1.w * b1.w;
            const float gv = w0 * fmaxf(a + lora0, 0.f) + w1 * fmaxf(a + lora1, 0.f);
            outg[(size_t)row * Fdim + f] = f2bf(gv);
          }
        }
      }
  } else {
    // split-K partial: atomic accumulate fp32 into outf[M][Ncols]
#pragma unroll
    for (int mh = 0; mh < 2; ++mh)
#pragma unroll
      for (int mi = 0; mi < 4; ++mi)
#pragma unroll
        for (int ni = 0; ni < 4; ++ni)
#pragma unroll
          for (int r = 0; r < 4; ++r) {
            const int row = bm + wm * 128 + mh * 64 + mi * 16 + lhi * 4 + r;
            const int col = bn + wn * 64 + ni * 16 + l16;
            unsafeAtomicAdd(&outf[(size_t)row * Ncols + col], acc[mh * 4 + mi][ni][r]);
          }
  }
}

extern "C" void kernel_launch(void* const* d_in, const int* in_sizes, int n_in,
                              void* d_out, int out_size, void* d_ws, size_t ws_size,
                              hipStream_t stream) {
  const float* x  = (const float*)d_in[0];
  const float* Wg = (const float*)d_in[1];
  const float* bg = (const float*)d_in[2];
  const float* Wi = (const float*)d_in[3];
  const float* Wo = (const float*)d_in[4];
  const float* Aw = (const float*)d_in[5];
  const float* B2 = (const float*)d_in[6];
  float* out = (float*)d_out;

  // workspace layout (bf16 as ushort)
  unsigned short* xb  = (unsigned short*)d_ws;                 // [BSz][Ddim]   8 MB
  unsigned short* wib = xb  + (size_t)BSz  * Ddim;             // [Fdim][Ddim]  8 MB
  unsigned short* wob = wib + (size_t)Fdim * Ddim;             // [Ddim][Fdim]  8 MB
  unsigned short* g   = wob + (size_t)Ddim * Fdim;             // [BSz][Fdim]  32 MB
  float* meta = (float*)(g + (size_t)BSz * Fdim);              // [BSz][16]   256 KB

  zero_f32<<<BSz * Ddim / 4 / 256, 256, 0, stream>>>(out, BSz * Ddim / 4);

  const int n4x = BSz * Ddim / 4;   // == Fdim*Ddim/4 == Ddim*Fdim/4
  cvt_kernel<<<(n4x + 255) / 256, 256, 0, stream>>>(x,  xb,  n4x);
  cvt_kernel<<<(n4x + 255) / 256, 256, 0, stream>>>(Wi, wib, n4x);
  cvt_kernel<<<(n4x + 255) / 256, 256, 0, stream>>>(Wo, wob, n4x);

  router_kernel<<<BSz, 256, 0, stream>>>(x, Wg, bg, Aw, meta);

  // GEMM1: base = x * Wi^T, fused MoE epilogue -> g (bf16)
  // 256^2 tile, 8-phase, grid 16x16 = 256 blocks (1/CU), K=1024
  gemm8p<0><<<dim3(Fdim / 256, BSz / 256, 1), 512, 0, stream>>>(
      xb, wib, Ddim, Ddim, Fdim, meta, B2, g, nullptr);

  // GEMM2: out = g * Wo^T, split-K x4 (each 1024), f32 atomicAdd into out
  // grid 4x16x4 = 256 blocks (1/CU)
  gemm8p<1><<<dim3(Ddim / 256, BSz / 256, 4), 512, 0, stream>>>(
      g, wob, Fdim, Fdim / 4, Ddim, nullptr, nullptr, nullptr, out);
}

// Round 5
// 192.644 us; speedup vs baseline: 1.0530x; 1.0081x over previous
//
#include <hip/hip_runtime.h>
#include <stdint.h>

#define BSz 4096   // B*S tokens
#define Ddim 1024
#define Fdim 4096
#define Edim 4
#define Rdim 4

typedef __attribute__((ext_vector_type(8))) short bf16x8;
typedef __attribute__((ext_vector_type(4))) float f32x4;

__device__ __forceinline__ unsigned short f2bf(float f) {
  union { float f; uint32_t u; } c; c.f = f;
  return (unsigned short)((c.u + 0x7fffu + ((c.u >> 16) & 1u)) >> 16);
}

#define BARX() do { asm volatile("" ::: "memory"); __builtin_amdgcn_s_barrier(); asm volatile("" ::: "memory"); } while (0)

// inline-asm ds_read_b128: opaque to SIInsertWaitcnts' LDS-DMA alias tracking,
// so the compiler cannot inject s_waitcnt vmcnt(0) before it. Caller MUST
// issue s_waitcnt lgkmcnt(0) + sched_barrier(0) before consuming the result.
__device__ __forceinline__ bf16x8 ldsr128(const unsigned short* p) {
  bf16x8 r;
  unsigned a = (unsigned)(uintptr_t)(const __attribute__((address_space(3))) void*)p;
  asm volatile("ds_read_b128 %0, %1" : "=v"(r) : "v"(a));
  return r;
}

// ---------------- zero d_out (deterministic base for split-K atomics) ----
__global__ __launch_bounds__(256) void zero_f32(float* __restrict__ p, int n4) {
  int i = blockIdx.x * 256 + threadIdx.x;
  if (i < n4) ((float4*)p)[i] = make_float4(0.f, 0.f, 0.f, 0.f);
}

// ---------------- fp32 -> bf16 conversion (vectorized) ----------------
__global__ __launch_bounds__(256) void cvt_kernel(const float* __restrict__ in,
                                                  unsigned short* __restrict__ out,
                                                  int n4) {
  int i = blockIdx.x * 256 + threadIdx.x;
  if (i < n4) {
    float4 v = ((const float4*)in)[i];
    ushort4 o;
    o.x = f2bf(v.x); o.y = f2bf(v.y); o.z = f2bf(v.z); o.w = f2bf(v.w);
    ((ushort4*)out)[i] = o;
  }
}

// ---------------- router: logits -> softmax -> top2 + lora_low ----------------
__global__ __launch_bounds__(256) void router_kernel(const float* __restrict__ x,
                                                     const float* __restrict__ Wg,
                                                     const float* __restrict__ bg,
                                                     const float* __restrict__ Aw,
                                                     float* __restrict__ meta) {
  __shared__ float xs[Ddim];
  __shared__ float dots[Edim + Edim * Rdim];
  const int t = blockIdx.x;
  const float4* xt = (const float4*)(x + (size_t)t * Ddim);
  for (int i = threadIdx.x; i < Ddim / 4; i += 256) ((float4*)xs)[i] = xt[i];
  __syncthreads();
  const int wave = threadIdx.x >> 6, lane = threadIdx.x & 63;
  for (int d = wave * 5; d < wave * 5 + 5; ++d) {
    const float* wrow = (d < Edim) ? (Wg + (size_t)d * Ddim)
                                   : (Aw + (size_t)(d - Edim) * Ddim);
    float s = 0.f;
    for (int i = lane; i < Ddim; i += 64) s += xs[i] * wrow[i];
    for (int off = 32; off; off >>= 1) s += __shfl_down(s, off);
    if (lane == 0) dots[d] = s;
  }
  __syncthreads();
  if (threadIdx.x == 0) {
    float p[Edim];
    float m = -1e30f;
    for (int e = 0; e < Edim; ++e) { p[e] = dots[e] + bg[e]; m = fmaxf(m, p[e]); }
    float sum = 0.f;
    for (int e = 0; e < Edim; ++e) { p[e] = expf(p[e] - m); sum += p[e]; }
    const float inv = 1.f / sum;
    for (int e = 0; e < Edim; ++e) p[e] *= inv;
    int e0 = 0;
    for (int e = 1; e < Edim; ++e) if (p[e] > p[e0]) e0 = e;
    int e1 = (e0 == 0) ? 1 : 0;
    for (int e = 0; e < Edim; ++e) if (e != e0 && p[e] > p[e1]) e1 = e;
    float* mt = meta + (size_t)t * 16;
    mt[0] = (float)e0; mt[1] = (float)e1; mt[2] = p[e0]; mt[3] = p[e1];
    for (int r = 0; r < Rdim; ++r) {
      mt[4 + r] = dots[Edim + e0 * Rdim + r];
      mt[8 + r] = dots[Edim + e1 * Rdim + r];
    }
    mt[12] = 0.f; mt[13] = 0.f; mt[14] = 0.f; mt[15] = 0.f;
  }
}

// ---------------- 8-phase 256x256 NT bf16 GEMM, asm ds_read frags --------
// C[M,N] = A[M,K] rows bm.. * B[N,K]^T rows bn.. over K-slice [kbase,+kslice).
// 8 waves (2M x 4N), BK=64 in 2 k-halves, LDS 128 KB (2 dbuf x 2 kh x A,B).
// Counted vmcnt(4) per k-half; frag reads are inline-asm ds_read_b128 so the
// compiler cannot insert vmcnt(0) drains (LDS-DMA alias protection).
// EPI==0: fused MoE epilogue -> outg bf16.  EPI==1: f32 atomicAdd into outf.
template <int EPI>
__global__ __launch_bounds__(512, 2)
void gemm8p(const unsigned short* __restrict__ Ag,
            const unsigned short* __restrict__ Bg,
            int K, int kslice, int Ncols,
            const float* __restrict__ meta,
            const float* __restrict__ B2,
            unsigned short* __restrict__ outg,
            float* __restrict__ outf) {
  __shared__ __align__(16) unsigned short sA[2 * 2 * 256 * 32];  // 64 KB
  __shared__ __align__(16) unsigned short sB[2 * 2 * 256 * 32];  // 64 KB

  const int tid = threadIdx.x;
  const int lane = tid & 63;
  const int wave = tid >> 6;            // 0..7
  const int wm = wave >> 2, wn = wave & 3;
  const int l16 = lane & 15, lhi = lane >> 4;

  // XCD-aware bijective swizzle on the xy grid (per z-slice)
  const int nwg = gridDim.x * gridDim.y;
  const int lin = blockIdx.y * gridDim.x + blockIdx.x;
  const int cpx = nwg >> 3;
  const int swz = (lin & 7) * cpx + (lin >> 3);
  const int bx = swz % gridDim.x, by = swz / gridDim.x;
  const int bm = by * 256, bn = bx * 256;
  const int kbase = blockIdx.z * kslice;
  const int NT = kslice / 64;

  f32x4 acc[8][4] = {};

  // staging geometry: thread covers 16B; row=tid>>2 (+128 for 2nd load)
  const int srow = tid >> 2;
  const int skoff = ((tid & 3) ^ ((srow >> 1) & 3)) * 8;   // inverse-swizzled src col
  // read-side swizzle (lane-constant): chunk = lhi ^ ((l16>>1)&3)
  const int rc8 = (lhi ^ ((l16 >> 1) & 3)) * 8;

  auto stageA = [&](int slot, int kh, int kt2) {
    unsigned short* reg = sA + ((slot * 2 + kh) << 13);
    const size_t g0 = (size_t)(bm + srow) * K + kbase + kt2 + kh * 32 + skoff;
    __builtin_amdgcn_global_load_lds(
        (const __attribute__((address_space(1))) void*)(Ag + g0),
        (__attribute__((address_space(3))) void*)(reg + tid * 8), 16, 0, 0);
    __builtin_amdgcn_global_load_lds(
        (const __attribute__((address_space(1))) void*)(Ag + g0 + (size_t)128 * K),
        (__attribute__((address_space(3))) void*)(reg + 4096 + tid * 8), 16, 0, 0);
  };
  auto stageB = [&](int slot, int kh, int kt2) {
    unsigned short* reg = sB + ((slot * 2 + kh) << 13);
    const size_t g0 = (size_t)(bn + srow) * K + kbase + kt2 + kh * 32 + skoff;
    __builtin_amdgcn_global_load_lds(
        (const __attribute__((address_space(1))) void*)(Bg + g0),
        (__attribute__((address_space(3))) void*)(reg + tid * 8), 16, 0, 0);
    __builtin_amdgcn_global_load_lds(
        (const __attribute__((address_space(1))) void*)(Bg + g0 + (size_t)128 * K),
        (__attribute__((address_space(3))) void*)(reg + 4096 + tid * 8), 16, 0, 0);
  };

  // prologue: tile 0 fully staged (order Ak0,Bk0,Ak1,Bk1) -> 8 loads/thread
  stageA(0, 0, 0); stageB(0, 0, 0); stageA(0, 1, 0); stageB(0, 1, 0);

  for (int t = 0; t < NT; ++t) {
    const int slot = t & 1, nslot = slot ^ 1;
    const int kt2n = (t + 1) * 64;
    const bool pf = (t + 1 < NT);

#pragma unroll
    for (int kh = 0; kh < 2; ++kh) {
      if (kh == 0 || pf) asm volatile("s_waitcnt vmcnt(4)" ::: "memory");
      else               asm volatile("s_waitcnt vmcnt(0)" ::: "memory");
      BARX();                                              // k-half landed for all
      const unsigned short* As = sA + ((slot * 2 + kh) << 13);
      const unsigned short* Bs = sB + ((slot * 2 + kh) << 13);
      bf16x8 bfr[4], afr[4];

      // ---- phase mh=0: frag reads (asm), stage A-half of t+1, 16 MFMA ----
#pragma unroll
      for (int ni = 0; ni < 4; ++ni)
        bfr[ni] = ldsr128(Bs + (wn * 64 + ni * 16 + l16) * 32 + rc8);
#pragma unroll
      for (int mi = 0; mi < 4; ++mi)
        afr[mi] = ldsr128(As + (wm * 128 + mi * 16 + l16) * 32 + rc8);
      if (pf) stageA(nslot, kh, kt2n);
      asm volatile("s_waitcnt lgkmcnt(0)" ::: "memory");
      __builtin_amdgcn_sched_barrier(0);
      __builtin_amdgcn_s_setprio(1);
#pragma unroll
      for (int mi = 0; mi < 4; ++mi)
#pragma unroll
        for (int ni = 0; ni < 4; ++ni)
          acc[mi][ni] = __builtin_amdgcn_mfma_f32_16x16x32_bf16(afr[mi], bfr[ni], acc[mi][ni], 0, 0, 0);
      __builtin_amdgcn_s_setprio(0);
      BARX();

      // ---- phase mh=1: frag reads rows+64 (asm), stage B-half of t+1, 16 MFMA ----
#pragma unroll
      for (int mi = 0; mi < 4; ++mi)
        afr[mi] = ldsr128(As + (wm * 128 + 64 + mi * 16 + l16) * 32 + rc8);
      if (pf) stageB(nslot, kh, kt2n);
      asm volatile("s_waitcnt lgkmcnt(0)" ::: "memory");
      __builtin_amdgcn_sched_barrier(0);
      __builtin_amdgcn_s_setprio(1);
#pragma unroll
      for (int mi = 0; mi < 4; ++mi)
#pragma unroll
        for (int ni = 0; ni < 4; ++ni)
          acc[4 + mi][ni] = __builtin_amdgcn_mfma_f32_16x16x32_bf16(afr[mi], bfr[ni], acc[4 + mi][ni], 0, 0, 0);
      __builtin_amdgcn_s_setprio(0);
      BARX();
    }
  }

  if (EPI == 0) {
    // g[t,f] = sum_{e in top2} w_e * relu(base + <ll_e, B2[e,f,:]>)
#pragma unroll
    for (int mh = 0; mh < 2; ++mh)
#pragma unroll
      for (int mi = 0; mi < 4; ++mi) {
#pragma unroll
        for (int r = 0; r < 4; ++r) {
          const int row = bm + wm * 128 + mh * 64 + mi * 16 + lhi * 4 + r;
          const float* mt = meta + (size_t)row * 16;
          const int e0 = (int)mt[0], e1 = (int)mt[1];
          const float w0 = mt[2], w1 = mt[3];
          const float4 l0 = *(const float4*)(mt + 4);
          const float4 l1 = *(const float4*)(mt + 8);
#pragma unroll
          for (int ni = 0; ni < 4; ++ni) {
            const int f = bn + wn * 64 + ni * 16 + l16;
            const float4 b0 = *(const float4*)(B2 + ((size_t)e0 * Fdim + f) * Rdim);
            const float4 b1 = *(const float4*)(B2 + ((size_t)e1 * Fdim + f) * Rdim);
            const float a = acc[mh * 4 + mi][ni][r];
            const float lora0 = l0.x * b0.x + l0.y * b0.y + l0.z * b0.z + l0.w * b0.w;
            const float lora1 = l1.x * b1.x + l1.y * b1.y + l1.z * b1.z + l1.w * b1.w;
            const float gv = w0 * fmaxf(a + lora0, 0.f) + w1 * fmaxf(a + lora1, 0.f);
            outg[(size_t)row * Fdim + f] = f2bf(gv);
          }
        }
      }
  } else {
    // split-K partial: atomic accumulate fp32 into outf[M][Ncols]
#pragma unroll
    for (int mh = 0; mh < 2; ++mh)
#pragma unroll
      for (int mi = 0; mi < 4; ++mi)
#pragma unroll
        for (int ni = 0; ni < 4; ++ni)
#pragma unroll
          for (int r = 0; r < 4; ++r) {
            const int row = bm + wm * 128 + mh * 64 + mi * 16 + lhi * 4 + r;
            const int col = bn + wn * 64 + ni * 16 + l16;
            unsafeAtomicAdd(&outf[(size_t)row * Ncols + col], acc[mh * 4 + mi][ni][r]);
          }
  }
}

extern "C" void kernel_launch(void* const* d_in, const int* in_sizes, int n_in,
                              void* d_out, int out_size, void* d_ws, size_t ws_size,
                              hipStream_t stream) {
  const float* x  = (const float*)d_in[0];
  const float* Wg = (const float*)d_in[1];
  const float* bg = (const float*)d_in[2];
  const float* Wi = (const float*)d_in[3];
  const float* Wo = (const float*)d_in[4];
  const float* Aw = (const float*)d_in[5];
  const float* B2 = (const float*)d_in[6];
  float* out = (float*)d_out;

  // workspace layout (bf16 as ushort)
  unsigned short* xb  = (unsigned short*)d_ws;                 // [BSz][Ddim]   8 MB
  unsigned short* wib = xb  + (size_t)BSz  * Ddim;             // [Fdim][Ddim]  8 MB
  unsigned short* wob = wib + (size_t)Fdim * Ddim;             // [Ddim][Fdim]  8 MB
  unsigned short* g   = wob + (size_t)Ddim * Fdim;             // [BSz][Fdim]  32 MB
  float* meta = (float*)(g + (size_t)BSz * Fdim);              // [BSz][16]   256 KB

  zero_f32<<<BSz * Ddim / 4 / 256, 256, 0, stream>>>(out, BSz * Ddim / 4);

  const int n4x = BSz * Ddim / 4;   // == Fdim*Ddim/4 == Ddim*Fdim/4
  cvt_kernel<<<(n4x + 255) / 256, 256, 0, stream>>>(x,  xb,  n4x);
  cvt_kernel<<<(n4x + 255) / 256, 256, 0, stream>>>(Wi, wib, n4x);
  cvt_kernel<<<(n4x + 255) / 256, 256, 0, stream>>>(Wo, wob, n4x);

  router_kernel<<<BSz, 256, 0, stream>>>(x, Wg, bg, Aw, meta);

  // GEMM1: base = x * Wi^T, fused MoE epilogue -> g (bf16)
  // 256^2 tile, 8-phase, grid 16x16 = 256 blocks (1/CU), K=1024
  gemm8p<0><<<dim3(Fdim / 256, BSz / 256, 1), 512, 0, stream>>>(
      xb, wib, Ddim, Ddim, Fdim, meta, B2, g, nullptr);

  // GEMM2: out = g * Wo^T, split-K x4 (each 1024), f32 atomicAdd into out
  // grid 4x16x4 = 256 blocks (1/CU)
  gemm8p<1><<<dim3(Ddim / 256, BSz / 256, 4), 512, 0, stream>>>(
      g, wob, Fdim, Fdim / 4, Ddim, nullptr, nullptr, nullptr, out);
}